// Round 3
// baseline (2594.291 us; speedup 1.0000x reference)
//
#include <hip/hip_runtime.h>
#include <math.h>

// ---------------- Kernel A: reciprocal row norms ----------------
__global__ void rownorm_kernel(const float* __restrict__ x,
                               float* __restrict__ rnorm, int C) {
    int row = blockIdx.x;
    const float4* xr = (const float4*)(x + (size_t)row * C);
    int n4 = C >> 2;
    float s = 0.f;
    for (int c = threadIdx.x; c < n4; c += blockDim.x) {
        float4 v = xr[c];
        s += v.x * v.x + v.y * v.y + v.z * v.z + v.w * v.w;
    }
    for (int off = 32; off > 0; off >>= 1) s += __shfl_down(s, off, 64);
    __shared__ float red[4];
    int lane = threadIdx.x & 63, wid = threadIdx.x >> 6;
    if (lane == 0) red[wid] = s;
    __syncthreads();
    if (threadIdx.x == 0) {
        float t = red[0] + red[1] + red[2] + red[3];
        float n = fmaxf(sqrtf(t), 1e-6f);
        rnorm[row] = 1.0f / n;
    }
}

// ---------------- Kernel B: cosine = 1 - xn @ xn^T (fp32 vector GEMM) ------
#define BM 128
#define BN 128
#define BK 32

__global__ __launch_bounds__(256) void cosine_gemm(
        const float* __restrict__ x, const float* __restrict__ rnorm,
        float* __restrict__ cosine, int L, int C) {
    __shared__ float As[BK][BM + 4];
    __shared__ float Bs[BK][BN + 4];
    const int tid = threadIdx.x;
    const int i0 = blockIdx.y * BM;
    const int j0 = blockIdx.x * BN;
    const int tr = (tid >> 4) << 3;
    const int tc = (tid & 15) << 3;
    const int lr = tid >> 3;
    const int lc = (tid & 7) << 2;
    float acc[8][8] = {};

    for (int k0 = 0; k0 < C; k0 += BK) {
#pragma unroll
        for (int q = 0; q < 4; ++q) {
            int r = lr + q * 32;
            float ra = rnorm[i0 + r];
            float4 va = *(const float4*)(x + (size_t)(i0 + r) * C + k0 + lc);
            As[lc + 0][r] = va.x * ra;
            As[lc + 1][r] = va.y * ra;
            As[lc + 2][r] = va.z * ra;
            As[lc + 3][r] = va.w * ra;
            float rb = rnorm[j0 + r];
            float4 vb = *(const float4*)(x + (size_t)(j0 + r) * C + k0 + lc);
            Bs[lc + 0][r] = vb.x * rb;
            Bs[lc + 1][r] = vb.y * rb;
            Bs[lc + 2][r] = vb.z * rb;
            Bs[lc + 3][r] = vb.w * rb;
        }
        __syncthreads();
#pragma unroll
        for (int kk = 0; kk < BK; ++kk) {
            float a[8], b[8];
#pragma unroll
            for (int m = 0; m < 8; ++m) a[m] = As[kk][tr + m];
#pragma unroll
            for (int n = 0; n < 8; ++n) b[n] = Bs[kk][tc + n];
#pragma unroll
            for (int m = 0; m < 8; ++m)
#pragma unroll
                for (int n = 0; n < 8; ++n)
                    acc[m][n] = fmaf(a[m], b[n], acc[m][n]);
        }
        __syncthreads();
    }
#pragma unroll
    for (int m = 0; m < 8; ++m) {
        float* crow = cosine + (size_t)(i0 + tr + m) * L + j0 + tc;
        float4 o0 = {1.f - acc[m][0], 1.f - acc[m][1], 1.f - acc[m][2], 1.f - acc[m][3]};
        float4 o1 = {1.f - acc[m][4], 1.f - acc[m][5], 1.f - acc[m][6], 1.f - acc[m][7]};
        ((float4*)crow)[0] = o0;
        ((float4*)crow)[1] = o1;
    }
}

// ---------------- Kernel C: second-smallest per row ----------------
__global__ void twosmallest_kernel(const float* __restrict__ cosine,
                                   float* __restrict__ min2, int L) {
    int row = blockIdx.x;
    const float4* r4 = (const float4*)(cosine + (size_t)row * L);
    int n4 = L >> 2;
    float m1 = INFINITY, m2 = INFINITY;
    for (int c = threadIdx.x; c < n4; c += blockDim.x) {
        float4 v = r4[c];
        float vv[4] = {v.x, v.y, v.z, v.w};
#pragma unroll
        for (int t = 0; t < 4; ++t) {
            float u = vv[t];
            if (u < m1) { m2 = m1; m1 = u; }
            else m2 = fminf(m2, u);
        }
    }
    for (int off = 32; off > 0; off >>= 1) {
        float om1 = __shfl_down(m1, off, 64);
        float om2 = __shfl_down(m2, off, 64);
        float nm1 = fminf(m1, om1);
        float nm2 = fminf(fmaxf(m1, om1), fminf(m2, om2));
        m1 = nm1; m2 = nm2;
    }
    __shared__ float s1[4], s2[4];
    int lane = threadIdx.x & 63, wid = threadIdx.x >> 6;
    if (lane == 0) { s1[wid] = m1; s2[wid] = m2; }
    __syncthreads();
    if (threadIdx.x == 0) {
        float a1 = s1[0], a2 = s2[0];
        for (int w = 1; w < 4; ++w) {
            float b1 = s1[w], b2 = s2[w];
            float n2 = fminf(fmaxf(a1, b1), fminf(a2, b2));
            a1 = fminf(a1, b1);
            a2 = n2;
        }
        min2[row] = a2;
    }
}

// ---------------- Kernel D: persistent greedy k-center ----------------
// 1 block x 256 threads (4 waves). Thread t owns scores [16t, 16t+16) in
// REGISTERS (all indexing compile-time; no runtime-indexed reg arrays).
// Per step: tournament-tree local argmax -> dual-shfl wave reduce ->
// LDS slots (parity double-buffered, one barrier) -> speculative load of
// ALL 4 candidate rows (latency overlaps the slot combine) -> static
// cndmask select of winner's data -> fused fmin update.
__global__ __launch_bounds__(256) void greedy_kernel(
        const float* __restrict__ cosine, const float* __restrict__ min2,
        float* __restrict__ sel_out, int L, int k) {
    const int tid = threadIdx.x;
    const int lane = tid & 63, wid = tid >> 6;
    __shared__ float sv[2][4];
    __shared__ int si[2][4];
    __shared__ int wsum[4];

    const int base = tid << 4;
    float sc[16];

    // ---- tournament argmax over 16 regs (first-max tie: left wins) ----
    auto tree16 = [&](const float* u, float& bv, int& bj) {
        float tv[8]; int tj[8];
#pragma unroll
        for (int t = 0; t < 8; ++t) {
            bool g = u[2 * t + 1] > u[2 * t];
            tv[t] = g ? u[2 * t + 1] : u[2 * t];
            tj[t] = g ? (base + 2 * t + 1) : (base + 2 * t);
        }
#pragma unroll
        for (int t = 0; t < 4; ++t) {
            bool g = tv[2 * t + 1] > tv[2 * t];
            tv[t] = g ? tv[2 * t + 1] : tv[2 * t];
            tj[t] = g ? tj[2 * t + 1] : tj[2 * t];
        }
#pragma unroll
        for (int t = 0; t < 2; ++t) {
            bool g = tv[2 * t + 1] > tv[2 * t];
            tv[t] = g ? tv[2 * t + 1] : tv[2 * t];
            tj[t] = g ? tj[2 * t + 1] : tj[2 * t];
        }
        bool g = tv[1] > tv[0];
        bv = g ? tv[1] : tv[0];
        bj = g ? tj[1] : tj[0];
    };

    // ---- wave reduce + slot exchange; returns (winner value via wv) ----
    auto block_reduce = [&](float bv, int bj, int p, float& wv, int& wi, int& win) {
#pragma unroll
        for (int off = 32; off > 0; off >>= 1) {
            float ov = __shfl_xor(bv, off, 64);
            int oj = __shfl_xor(bj, off, 64);
            bool t = (ov > bv) || (ov == bv && oj < bj);
            bv = t ? ov : bv;
            bj = t ? oj : bj;
        }
        if (lane == 0) { sv[p][wid] = bv; si[p][wid] = bj; }
        __syncthreads();
    };

    float bv; int bj;

    // ---- first = argmax(min2) ----
    {
        const float4* m4 = (const float4*)min2 + (tid << 2);
        float4 q0 = m4[0], q1 = m4[1], q2 = m4[2], q3 = m4[3];
        float u[16] = {q0.x, q0.y, q0.z, q0.w, q1.x, q1.y, q1.z, q1.w,
                       q2.x, q2.y, q2.z, q2.w, q3.x, q3.y, q3.z, q3.w};
        tree16(u, bv, bj);
        float wv; int wi, win;
        block_reduce(bv, bj, 0, wv, wi, win);
        // combine slots (all threads redundantly)
        float cv0 = sv[0][0], cv1 = sv[0][1], cv2 = sv[0][2], cv3 = sv[0][3];
        int ci0 = si[0][0], ci1 = si[0][1], ci2 = si[0][2], ci3 = si[0][3];
        wv = cv0; wi = ci0;
        if (cv1 > wv || (cv1 == wv && ci1 < wi)) { wv = cv1; wi = ci1; }
        if (cv2 > wv || (cv2 == wv && ci2 < wi)) { wv = cv2; wi = ci2; }
        if (cv3 > wv || (cv3 == wv && ci3 < wi)) { wv = cv3; wi = ci3; }
        int first = wi;
        // scores = cosine[first], poke -inf branchlessly
        const float4* rp = (const float4*)(cosine + (size_t)first * L) + (tid << 2);
        float4 r0 = rp[0], r1 = rp[1], r2 = rp[2], r3 = rp[3];
        float rr[16] = {r0.x, r0.y, r0.z, r0.w, r1.x, r1.y, r1.z, r1.w,
                        r2.x, r2.y, r2.z, r2.w, r3.x, r3.y, r3.z, r3.w};
        int sel_local = ((first >> 4) == tid) ? (first & 15) : -1;
#pragma unroll
        for (int j = 0; j < 16; ++j)
            sc[j] = (j == sel_local) ? -INFINITY : rr[j];
        tree16(sc, bv, bj);
    }

    // ---- k-1 greedy steps ----
    int p = 1;
    for (int it = 0; it < k - 1; ++it) {
        float wv; int wi, win;
        block_reduce(bv, bj, p, wv, wi, win);
        // read 4 candidates
        float cv0 = sv[p][0], cv1 = sv[p][1], cv2 = sv[p][2], cv3 = sv[p][3];
        int ci0 = si[p][0], ci1 = si[p][1], ci2 = si[p][2], ci3 = si[p][3];
        p ^= 1;
        // speculative loads: all 4 candidate rows at own slice (in flight together)
        const float4* rp0 = (const float4*)(cosine + (size_t)ci0 * L) + (tid << 2);
        const float4* rp1 = (const float4*)(cosine + (size_t)ci1 * L) + (tid << 2);
        const float4* rp2 = (const float4*)(cosine + (size_t)ci2 * L) + (tid << 2);
        const float4* rp3 = (const float4*)(cosine + (size_t)ci3 * L) + (tid << 2);
        float4 a0 = rp0[0], a1 = rp0[1], a2 = rp0[2], a3 = rp0[3];
        float4 b0 = rp1[0], b1 = rp1[1], b2 = rp1[2], b3 = rp1[3];
        float4 c0 = rp2[0], c1 = rp2[1], c2 = rp2[2], c3 = rp2[3];
        float4 d0 = rp3[0], d1 = rp3[1], d2 = rp3[2], d3 = rp3[3];
        // combine candidates while loads fly
        wv = cv0; wi = ci0; win = 0;
        if (cv1 > wv || (cv1 == wv && ci1 < wi)) { wv = cv1; wi = ci1; win = 1; }
        if (cv2 > wv || (cv2 == wv && ci2 < wi)) { wv = cv2; wi = ci2; win = 2; }
        if (cv3 > wv || (cv3 == wv && ci3 < wi)) { wv = cv3; wi = ci3; win = 3; }
        bool lo = (win & 1) != 0, hi = (win & 2) != 0;
        // static 2-level select of winner's row data
        float4 s0, s1, s2, s3;
        {
            float4 x0 = lo ? b0 : a0, y0 = lo ? d0 : c0; s0 = hi ? y0 : x0;
            float4 x1 = lo ? b1 : a1, y1 = lo ? d1 : c1; s1 = hi ? y1 : x1;
            float4 x2 = lo ? b2 : a2, y2 = lo ? d2 : c2; s2 = hi ? y2 : x2;
            float4 x3 = lo ? b3 : a3, y3 = lo ? d3 : c3; s3 = hi ? y3 : x3;
        }
        float rr[16] = {s0.x, s0.y, s0.z, s0.w, s1.x, s1.y, s1.z, s1.w,
                        s2.x, s2.y, s2.z, s2.w, s3.x, s3.y, s3.z, s3.w};
        int sel_local = ((wi >> 4) == tid) ? (wi & 15) : -1;
#pragma unroll
        for (int j = 0; j < 16; ++j) {
            float m = fminf(sc[j], rr[j]);
            sc[j] = (j == sel_local) ? -INFINITY : m;
        }
        tree16(sc, bv, bj);
    }

    // ---- compact selected (score == -inf) in ascending index order ----
    unsigned flags = 0; int cnt = 0;
#pragma unroll
    for (int j = 0; j < 16; ++j)
        if (sc[j] == -INFINITY) { flags |= 1u << j; ++cnt; }
    int incl = cnt;
#pragma unroll
    for (int off = 1; off < 64; off <<= 1) {
        int n = __shfl_up(incl, off, 64);
        if (lane >= off) incl += n;
    }
    if (lane == 63) wsum[wid] = incl;
    __syncthreads();
    int off0 = 0;
#pragma unroll
    for (int w = 0; w < 4; ++w)
        if (w < wid) off0 += wsum[w];
    int pos = off0 + incl - cnt;
#pragma unroll
    for (int j = 0; j < 16; ++j)
        if ((flags >> j) & 1) sel_out[pos++] = (float)(base + j);
}

// ---------------- launch ----------------
extern "C" void kernel_launch(void* const* d_in, const int* in_sizes, int n_in,
                              void* d_out, int out_size, void* d_ws, size_t ws_size,
                              hipStream_t stream) {
    const float* x = (const float*)d_in[0];

    long long L = (long long)floor(sqrt((double)out_size));
    while (L * L > (long long)out_size) --L;
    while ((L + 1) * (L + 1) <= (long long)out_size) ++L;
    long long k = (long long)out_size - L * L;
    long long C = (long long)in_sizes[0] / L;

    float* sel = (float*)d_out;
    float* cosine = (float*)d_out + k;
    float* rnorm = (float*)d_ws;
    float* min2 = rnorm + L;

    rownorm_kernel<<<(int)L, 256, 0, stream>>>(x, rnorm, (int)C);
    dim3 g2((int)(L / BN), (int)(L / BM));
    cosine_gemm<<<g2, 256, 0, stream>>>(x, rnorm, cosine, (int)L, (int)C);
    twosmallest_kernel<<<(int)L, 256, 0, stream>>>(cosine, min2, (int)L);
    greedy_kernel<<<1, 256, 0, stream>>>(cosine, min2, sel, (int)L, (int)k);
}

// Round 4
// 2082.687 us; speedup vs baseline: 1.2456x; 1.2456x over previous
//
#include <hip/hip_runtime.h>
#include <math.h>

// ---------------- Kernel A: reciprocal row norms ----------------
__global__ void rownorm_kernel(const float* __restrict__ x,
                               float* __restrict__ rnorm, int C) {
    int row = blockIdx.x;
    const float4* xr = (const float4*)(x + (size_t)row * C);
    int n4 = C >> 2;
    float s = 0.f;
    for (int c = threadIdx.x; c < n4; c += blockDim.x) {
        float4 v = xr[c];
        s += v.x * v.x + v.y * v.y + v.z * v.z + v.w * v.w;
    }
    for (int off = 32; off > 0; off >>= 1) s += __shfl_down(s, off, 64);
    __shared__ float red[4];
    int lane = threadIdx.x & 63, wid = threadIdx.x >> 6;
    if (lane == 0) red[wid] = s;
    __syncthreads();
    if (threadIdx.x == 0) {
        float t = red[0] + red[1] + red[2] + red[3];
        float n = fmaxf(sqrtf(t), 1e-6f);
        rnorm[row] = 1.0f / n;
    }
}

// ---------------- Kernel B: cosine = 1 - xn @ xn^T (fp32 vector GEMM) ------
#define BM 128
#define BN 128
#define BK 32

__global__ __launch_bounds__(256) void cosine_gemm(
        const float* __restrict__ x, const float* __restrict__ rnorm,
        float* __restrict__ cosine, int L, int C) {
    __shared__ float As[BK][BM + 4];
    __shared__ float Bs[BK][BN + 4];
    const int tid = threadIdx.x;
    const int i0 = blockIdx.y * BM;
    const int j0 = blockIdx.x * BN;
    const int tr = (tid >> 4) << 3;
    const int tc = (tid & 15) << 3;
    const int lr = tid >> 3;
    const int lc = (tid & 7) << 2;
    float acc[8][8] = {};

    for (int k0 = 0; k0 < C; k0 += BK) {
#pragma unroll
        for (int q = 0; q < 4; ++q) {
            int r = lr + q * 32;
            float ra = rnorm[i0 + r];
            float4 va = *(const float4*)(x + (size_t)(i0 + r) * C + k0 + lc);
            As[lc + 0][r] = va.x * ra;
            As[lc + 1][r] = va.y * ra;
            As[lc + 2][r] = va.z * ra;
            As[lc + 3][r] = va.w * ra;
            float rb = rnorm[j0 + r];
            float4 vb = *(const float4*)(x + (size_t)(j0 + r) * C + k0 + lc);
            Bs[lc + 0][r] = vb.x * rb;
            Bs[lc + 1][r] = vb.y * rb;
            Bs[lc + 2][r] = vb.z * rb;
            Bs[lc + 3][r] = vb.w * rb;
        }
        __syncthreads();
#pragma unroll
        for (int kk = 0; kk < BK; ++kk) {
            float a[8], b[8];
#pragma unroll
            for (int m = 0; m < 8; ++m) a[m] = As[kk][tr + m];
#pragma unroll
            for (int n = 0; n < 8; ++n) b[n] = Bs[kk][tc + n];
#pragma unroll
            for (int m = 0; m < 8; ++m)
#pragma unroll
                for (int n = 0; n < 8; ++n)
                    acc[m][n] = fmaf(a[m], b[n], acc[m][n]);
        }
        __syncthreads();
    }
#pragma unroll
    for (int m = 0; m < 8; ++m) {
        float* crow = cosine + (size_t)(i0 + tr + m) * L + j0 + tc;
        float4 o0 = {1.f - acc[m][0], 1.f - acc[m][1], 1.f - acc[m][2], 1.f - acc[m][3]};
        float4 o1 = {1.f - acc[m][4], 1.f - acc[m][5], 1.f - acc[m][6], 1.f - acc[m][7]};
        ((float4*)crow)[0] = o0;
        ((float4*)crow)[1] = o1;
    }
}

// ---------------- Kernel C: second-smallest per row ----------------
__global__ void twosmallest_kernel(const float* __restrict__ cosine,
                                   float* __restrict__ min2, int L) {
    int row = blockIdx.x;
    const float4* r4 = (const float4*)(cosine + (size_t)row * L);
    int n4 = L >> 2;
    float m1 = INFINITY, m2 = INFINITY;
    for (int c = threadIdx.x; c < n4; c += blockDim.x) {
        float4 v = r4[c];
        float vv[4] = {v.x, v.y, v.z, v.w};
#pragma unroll
        for (int t = 0; t < 4; ++t) {
            float u = vv[t];
            if (u < m1) { m2 = m1; m1 = u; }
            else m2 = fminf(m2, u);
        }
    }
    for (int off = 32; off > 0; off >>= 1) {
        float om1 = __shfl_down(m1, off, 64);
        float om2 = __shfl_down(m2, off, 64);
        float nm1 = fminf(m1, om1);
        float nm2 = fminf(fmaxf(m1, om1), fminf(m2, om2));
        m1 = nm1; m2 = nm2;
    }
    __shared__ float s1[4], s2[4];
    int lane = threadIdx.x & 63, wid = threadIdx.x >> 6;
    if (lane == 0) { s1[wid] = m1; s2[wid] = m2; }
    __syncthreads();
    if (threadIdx.x == 0) {
        float a1 = s1[0], a2 = s2[0];
        for (int w = 1; w < 4; ++w) {
            float b1 = s1[w], b2 = s2[w];
            float n2 = fminf(fmaxf(a1, b1), fminf(a2, b2));
            a1 = fminf(a1, b1);
            a2 = n2;
        }
        min2[row] = a2;
    }
}

// ---------------- Kernel D: persistent greedy k-center ----------------
// 1 block x 256 threads. Thread t owns scores [16t,16t+16) in 16 NAMED
// SCALARS (no register arrays anywhere in the hot loop -> no scratch).
// Per step: 15-node tournament local argmax -> wave shfl reduce -> wave
// prefetch of its own candidate row (stride-128B line touches, kept in
// flight across a hand-rolled barrier that skips the vmcnt drain) ->
// LDS slot combine -> winner-row slice load (L2-warmed) -> fused fmin+poke.
#define FOR16(X) X(0) X(1) X(2) X(3) X(4) X(5) X(6) X(7) \
                 X(8) X(9) X(10) X(11) X(12) X(13) X(14) X(15)

#define ARGMAX16(BV, BJ)                                                      \
  do {                                                                        \
    float _t0,_t1,_t2,_t3,_t4,_t5,_t6,_t7;                                    \
    int _u0,_u1,_u2,_u3,_u4,_u5,_u6,_u7;                                      \
    bool _g;                                                                  \
    _g = sc1  > sc0;  _t0 = _g ? sc1  : sc0;  _u0 = _g ? base+1  : base+0;    \
    _g = sc3  > sc2;  _t1 = _g ? sc3  : sc2;  _u1 = _g ? base+3  : base+2;    \
    _g = sc5  > sc4;  _t2 = _g ? sc5  : sc4;  _u2 = _g ? base+5  : base+4;    \
    _g = sc7  > sc6;  _t3 = _g ? sc7  : sc6;  _u3 = _g ? base+7  : base+6;    \
    _g = sc9  > sc8;  _t4 = _g ? sc9  : sc8;  _u4 = _g ? base+9  : base+8;    \
    _g = sc11 > sc10; _t5 = _g ? sc11 : sc10; _u5 = _g ? base+11 : base+10;   \
    _g = sc13 > sc12; _t6 = _g ? sc13 : sc12; _u6 = _g ? base+13 : base+12;   \
    _g = sc15 > sc14; _t7 = _g ? sc15 : sc14; _u7 = _g ? base+15 : base+14;   \
    _g = _t1 > _t0; _t0 = _g ? _t1 : _t0; _u0 = _g ? _u1 : _u0;               \
    _g = _t3 > _t2; _t2 = _g ? _t3 : _t2; _u2 = _g ? _u3 : _u2;               \
    _g = _t5 > _t4; _t4 = _g ? _t5 : _t4; _u4 = _g ? _u5 : _u4;               \
    _g = _t7 > _t6; _t6 = _g ? _t7 : _t6; _u6 = _g ? _u7 : _u6;               \
    _g = _t2 > _t0; _t0 = _g ? _t2 : _t0; _u0 = _g ? _u2 : _u0;               \
    _g = _t6 > _t4; _t4 = _g ? _t6 : _t4; _u4 = _g ? _u6 : _u4;               \
    _g = _t4 > _t0; BV = _g ? _t4 : _t0; BJ = _g ? _u4 : _u0;                 \
  } while (0)

// barrier that does NOT drain vmcnt (keeps prefetch fills in flight)
#define BAR_NOVM()                                                \
  do {                                                            \
    asm volatile("s_waitcnt lgkmcnt(0)" ::: "memory");            \
    __builtin_amdgcn_s_barrier();                                 \
    asm volatile("" ::: "memory");                                \
  } while (0)

static __device__ __forceinline__ void wreduce(float& bv, int& bj) {
#pragma unroll
    for (int off = 32; off > 0; off >>= 1) {
        float ov = __shfl_xor(bv, off, 64);
        int oj = __shfl_xor(bj, off, 64);
        bool t = (ov > bv) || (ov == bv && oj < bj);
        bv = t ? ov : bv;
        bj = t ? oj : bj;
    }
}

__global__ __launch_bounds__(256) void greedy_kernel(
        const float* __restrict__ cosine, const float* __restrict__ min2,
        float* __restrict__ sel_out, int L, int k) {
    const int tid = threadIdx.x;
    const int lane = tid & 63, wid = tid >> 6;
    __shared__ __align__(16) float sv[2][4];
    __shared__ __align__(16) int si[2][4];
    __shared__ int wsum[4];
    const int base = tid << 4;

#define DECL_SC(i) float sc##i;
    FOR16(DECL_SC)

    float bv; int bj;

    // ---- first = argmax(min2) ----
    {
        const float4* m4 = (const float4*)min2 + (tid << 2);
        float4 q0 = m4[0], q1 = m4[1], q2 = m4[2], q3 = m4[3];
        sc0 = q0.x;  sc1 = q0.y;  sc2 = q0.z;  sc3 = q0.w;
        sc4 = q1.x;  sc5 = q1.y;  sc6 = q1.z;  sc7 = q1.w;
        sc8 = q2.x;  sc9 = q2.y;  sc10 = q2.z; sc11 = q2.w;
        sc12 = q3.x; sc13 = q3.y; sc14 = q3.z; sc15 = q3.w;
    }
    ARGMAX16(bv, bj);
    wreduce(bv, bj);
    if (lane == 0) { sv[0][wid] = bv; si[0][wid] = bj; }
    BAR_NOVM();
    int first;
    {
        float4 cv4 = *(const float4*)&sv[0][0];
        int4 ci4 = *(const int4*)&si[0][0];
        float wv = cv4.x; int wi = ci4.x;
        if (cv4.y > wv || (cv4.y == wv && ci4.y < wi)) { wv = cv4.y; wi = ci4.y; }
        if (cv4.z > wv || (cv4.z == wv && ci4.z < wi)) { wv = cv4.z; wi = ci4.z; }
        if (cv4.w > wv || (cv4.w == wv && ci4.w < wi)) { wv = cv4.w; wi = ci4.w; }
        first = wi;
    }
    {
        const float4* rp = (const float4*)(cosine + (size_t)first * L) + (tid << 2);
        float4 q0 = rp[0], q1 = rp[1], q2 = rp[2], q3 = rp[3];
        int sl = ((first >> 4) == tid) ? (first & 15) : -1;
        sc0  = (sl == 0)  ? -INFINITY : q0.x;
        sc1  = (sl == 1)  ? -INFINITY : q0.y;
        sc2  = (sl == 2)  ? -INFINITY : q0.z;
        sc3  = (sl == 3)  ? -INFINITY : q0.w;
        sc4  = (sl == 4)  ? -INFINITY : q1.x;
        sc5  = (sl == 5)  ? -INFINITY : q1.y;
        sc6  = (sl == 6)  ? -INFINITY : q1.z;
        sc7  = (sl == 7)  ? -INFINITY : q1.w;
        sc8  = (sl == 8)  ? -INFINITY : q2.x;
        sc9  = (sl == 9)  ? -INFINITY : q2.y;
        sc10 = (sl == 10) ? -INFINITY : q2.z;
        sc11 = (sl == 11) ? -INFINITY : q2.w;
        sc12 = (sl == 12) ? -INFINITY : q3.x;
        sc13 = (sl == 13) ? -INFINITY : q3.y;
        sc14 = (sl == 14) ? -INFINITY : q3.z;
        sc15 = (sl == 15) ? -INFINITY : q3.w;
    }
    ARGMAX16(bv, bj);

    // ---- k-1 greedy steps, one (vmcnt-preserving) barrier each ----
    int p = 1;
    for (int it = 0; it < k - 1; ++it) {
        wreduce(bv, bj);
        if (lane == 0) { sv[p][wid] = bv; si[p][wid] = bj; }
        // wave prefetch: touch all 128-byte lines of own candidate row
        float pf0, pf1;
        {
            int ci = __builtin_amdgcn_readfirstlane(bj);
            const float* prow = cosine + (size_t)ci * (size_t)L;
            pf0 = prow[lane << 5];
            pf1 = prow[2048 + (lane << 5)];
        }
        BAR_NOVM();
        float4 cv4 = *(const float4*)&sv[p][0];
        int4 ci4 = *(const int4*)&si[p][0];
        p ^= 1;
        float wv = cv4.x; int wi = ci4.x;
        if (cv4.y > wv || (cv4.y == wv && ci4.y < wi)) { wv = cv4.y; wi = ci4.y; }
        if (cv4.z > wv || (cv4.z == wv && ci4.z < wi)) { wv = cv4.z; wi = ci4.z; }
        if (cv4.w > wv || (cv4.w == wv && ci4.w < wi)) { wv = cv4.w; wi = ci4.w; }
        const float4* rp = (const float4*)(cosine + (size_t)wi * L) + (tid << 2);
        float4 q0 = rp[0], q1 = rp[1], q2 = rp[2], q3 = rp[3];
        int sl = ((wi >> 4) == tid) ? (wi & 15) : -1;
        sc0  = (sl == 0)  ? -INFINITY : fminf(sc0, q0.x);
        sc1  = (sl == 1)  ? -INFINITY : fminf(sc1, q0.y);
        sc2  = (sl == 2)  ? -INFINITY : fminf(sc2, q0.z);
        sc3  = (sl == 3)  ? -INFINITY : fminf(sc3, q0.w);
        sc4  = (sl == 4)  ? -INFINITY : fminf(sc4, q1.x);
        sc5  = (sl == 5)  ? -INFINITY : fminf(sc5, q1.y);
        sc6  = (sl == 6)  ? -INFINITY : fminf(sc6, q1.z);
        sc7  = (sl == 7)  ? -INFINITY : fminf(sc7, q1.w);
        sc8  = (sl == 8)  ? -INFINITY : fminf(sc8, q2.x);
        sc9  = (sl == 9)  ? -INFINITY : fminf(sc9, q2.y);
        sc10 = (sl == 10) ? -INFINITY : fminf(sc10, q2.z);
        sc11 = (sl == 11) ? -INFINITY : fminf(sc11, q2.w);
        sc12 = (sl == 12) ? -INFINITY : fminf(sc12, q3.x);
        sc13 = (sl == 13) ? -INFINITY : fminf(sc13, q3.y);
        sc14 = (sl == 14) ? -INFINITY : fminf(sc14, q3.z);
        sc15 = (sl == 15) ? -INFINITY : fminf(sc15, q3.w);
        ARGMAX16(bv, bj);
        asm volatile("" :: "v"(pf0), "v"(pf1));  // keep prefetch alive
    }

    // ---- compact selected (score == -inf) in ascending index order ----
    unsigned flags = 0; int cnt = 0;
#define FLAGBIT(i) if (sc##i == -INFINITY) { flags |= (1u << i); ++cnt; }
    FOR16(FLAGBIT)
    int incl = cnt;
#pragma unroll
    for (int off = 1; off < 64; off <<= 1) {
        int n = __shfl_up(incl, off, 64);
        if (lane >= off) incl += n;
    }
    if (lane == 63) wsum[wid] = incl;
    __syncthreads();
    int off0 = 0;
#pragma unroll
    for (int w = 0; w < 4; ++w)
        if (w < wid) off0 += wsum[w];
    int pos = off0 + incl - cnt;
#pragma unroll
    for (int j = 0; j < 16; ++j)
        if ((flags >> j) & 1) sel_out[pos++] = (float)(base + j);
}

// ---------------- launch ----------------
extern "C" void kernel_launch(void* const* d_in, const int* in_sizes, int n_in,
                              void* d_out, int out_size, void* d_ws, size_t ws_size,
                              hipStream_t stream) {
    const float* x = (const float*)d_in[0];

    long long L = (long long)floor(sqrt((double)out_size));
    while (L * L > (long long)out_size) --L;
    while ((L + 1) * (L + 1) <= (long long)out_size) ++L;
    long long k = (long long)out_size - L * L;
    long long C = (long long)in_sizes[0] / L;

    float* sel = (float*)d_out;
    float* cosine = (float*)d_out + k;
    float* rnorm = (float*)d_ws;
    float* min2 = rnorm + L;

    rownorm_kernel<<<(int)L, 256, 0, stream>>>(x, rnorm, (int)C);
    dim3 g2((int)(L / BN), (int)(L / BM));
    cosine_gemm<<<g2, 256, 0, stream>>>(x, rnorm, cosine, (int)L, (int)C);
    twosmallest_kernel<<<(int)L, 256, 0, stream>>>(cosine, min2, (int)L);
    greedy_kernel<<<1, 256, 0, stream>>>(cosine, min2, sel, (int)L, (int)k);
}

// Round 5
// 1657.542 us; speedup vs baseline: 1.5651x; 1.2565x over previous
//
#include <hip/hip_runtime.h>
#include <math.h>

// ---------------- Kernel A: reciprocal row norms ----------------
__global__ void rownorm_kernel(const float* __restrict__ x,
                               float* __restrict__ rnorm, int C) {
    int row = blockIdx.x;
    const float4* xr = (const float4*)(x + (size_t)row * C);
    int n4 = C >> 2;
    float s = 0.f;
    for (int c = threadIdx.x; c < n4; c += blockDim.x) {
        float4 v = xr[c];
        s += v.x * v.x + v.y * v.y + v.z * v.z + v.w * v.w;
    }
    for (int off = 32; off > 0; off >>= 1) s += __shfl_down(s, off, 64);
    __shared__ float red[4];
    int lane = threadIdx.x & 63, wid = threadIdx.x >> 6;
    if (lane == 0) red[wid] = s;
    __syncthreads();
    if (threadIdx.x == 0) {
        float t = red[0] + red[1] + red[2] + red[3];
        float n = fmaxf(sqrtf(t), 1e-6f);
        rnorm[row] = 1.0f / n;
    }
}

// ---------------- Kernel B: cosine = 1 - xn @ xn^T (fp32 vector GEMM) ------
#define BM 128
#define BN 128
#define BK 32

__global__ __launch_bounds__(256) void cosine_gemm(
        const float* __restrict__ x, const float* __restrict__ rnorm,
        float* __restrict__ cosine, int L, int C) {
    __shared__ float As[BK][BM + 4];
    __shared__ float Bs[BK][BN + 4];
    const int tid = threadIdx.x;
    const int i0 = blockIdx.y * BM;
    const int j0 = blockIdx.x * BN;
    const int tr = (tid >> 4) << 3;
    const int tc = (tid & 15) << 3;
    const int lr = tid >> 3;
    const int lc = (tid & 7) << 2;
    float acc[8][8] = {};

    for (int k0 = 0; k0 < C; k0 += BK) {
#pragma unroll
        for (int q = 0; q < 4; ++q) {
            int r = lr + q * 32;
            float ra = rnorm[i0 + r];
            float4 va = *(const float4*)(x + (size_t)(i0 + r) * C + k0 + lc);
            As[lc + 0][r] = va.x * ra;
            As[lc + 1][r] = va.y * ra;
            As[lc + 2][r] = va.z * ra;
            As[lc + 3][r] = va.w * ra;
            float rb = rnorm[j0 + r];
            float4 vb = *(const float4*)(x + (size_t)(j0 + r) * C + k0 + lc);
            Bs[lc + 0][r] = vb.x * rb;
            Bs[lc + 1][r] = vb.y * rb;
            Bs[lc + 2][r] = vb.z * rb;
            Bs[lc + 3][r] = vb.w * rb;
        }
        __syncthreads();
#pragma unroll
        for (int kk = 0; kk < BK; ++kk) {
            float a[8], b[8];
#pragma unroll
            for (int m = 0; m < 8; ++m) a[m] = As[kk][tr + m];
#pragma unroll
            for (int n = 0; n < 8; ++n) b[n] = Bs[kk][tc + n];
#pragma unroll
            for (int m = 0; m < 8; ++m)
#pragma unroll
                for (int n = 0; n < 8; ++n)
                    acc[m][n] = fmaf(a[m], b[n], acc[m][n]);
        }
        __syncthreads();
    }
#pragma unroll
    for (int m = 0; m < 8; ++m) {
        float* crow = cosine + (size_t)(i0 + tr + m) * L + j0 + tc;
        float4 o0 = {1.f - acc[m][0], 1.f - acc[m][1], 1.f - acc[m][2], 1.f - acc[m][3]};
        float4 o1 = {1.f - acc[m][4], 1.f - acc[m][5], 1.f - acc[m][6], 1.f - acc[m][7]};
        ((float4*)crow)[0] = o0;
        ((float4*)crow)[1] = o1;
    }
}

// ---------------- Kernel C: second-smallest per row ----------------
__global__ void twosmallest_kernel(const float* __restrict__ cosine,
                                   float* __restrict__ min2, int L) {
    int row = blockIdx.x;
    const float4* r4 = (const float4*)(cosine + (size_t)row * L);
    int n4 = L >> 2;
    float m1 = INFINITY, m2 = INFINITY;
    for (int c = threadIdx.x; c < n4; c += blockDim.x) {
        float4 v = r4[c];
        float vv[4] = {v.x, v.y, v.z, v.w};
#pragma unroll
        for (int t = 0; t < 4; ++t) {
            float u = vv[t];
            if (u < m1) { m2 = m1; m1 = u; }
            else m2 = fminf(m2, u);
        }
    }
    for (int off = 32; off > 0; off >>= 1) {
        float om1 = __shfl_down(m1, off, 64);
        float om2 = __shfl_down(m2, off, 64);
        float nm1 = fminf(m1, om1);
        float nm2 = fminf(fmaxf(m1, om1), fminf(m2, om2));
        m1 = nm1; m2 = nm2;
    }
    __shared__ float s1[4], s2[4];
    int lane = threadIdx.x & 63, wid = threadIdx.x >> 6;
    if (lane == 0) { s1[wid] = m1; s2[wid] = m2; }
    __syncthreads();
    if (threadIdx.x == 0) {
        float a1 = s1[0], a2 = s2[0];
        for (int w = 1; w < 4; ++w) {
            float b1 = s1[w], b2 = s2[w];
            float n2 = fminf(fmaxf(a1, b1), fminf(a2, b2));
            a1 = fminf(a1, b1);
            a2 = n2;
        }
        min2[row] = a2;
    }
}

// ---------------- Kernel D: persistent greedy k-center ----------------
// 1 block x 256 threads (4 waves). Thread t owns scores [16t,16t+16) in 16
// named scalars. Per step: 15-node tournament local argmax -> DPP wave
// max-reduce (VALU-speed, replaces ds_bpermute butterfly) + ballot/readlane
// argmax recovery -> LDS slot combine (parity dbuf, one barrier) -> winner
// row slice load -> fused fmin + -inf poke.
#define FOR16(X) X(0) X(1) X(2) X(3) X(4) X(5) X(6) X(7) \
                 X(8) X(9) X(10) X(11) X(12) X(13) X(14) X(15)

#define ARGMAX16(BV, BJ)                                                      \
  do {                                                                        \
    float _t0,_t1,_t2,_t3,_t4,_t5,_t6,_t7;                                    \
    int _u0,_u1,_u2,_u3,_u4,_u5,_u6,_u7;                                      \
    bool _g;                                                                  \
    _g = sc1  > sc0;  _t0 = _g ? sc1  : sc0;  _u0 = _g ? base+1  : base+0;    \
    _g = sc3  > sc2;  _t1 = _g ? sc3  : sc2;  _u1 = _g ? base+3  : base+2;    \
    _g = sc5  > sc4;  _t2 = _g ? sc5  : sc4;  _u2 = _g ? base+5  : base+4;    \
    _g = sc7  > sc6;  _t3 = _g ? sc7  : sc6;  _u3 = _g ? base+7  : base+6;    \
    _g = sc9  > sc8;  _t4 = _g ? sc9  : sc8;  _u4 = _g ? base+9  : base+8;    \
    _g = sc11 > sc10; _t5 = _g ? sc11 : sc10; _u5 = _g ? base+11 : base+10;   \
    _g = sc13 > sc12; _t6 = _g ? sc13 : sc12; _u6 = _g ? base+13 : base+12;   \
    _g = sc15 > sc14; _t7 = _g ? sc15 : sc14; _u7 = _g ? base+15 : base+14;   \
    _g = _t1 > _t0; _t0 = _g ? _t1 : _t0; _u0 = _g ? _u1 : _u0;               \
    _g = _t3 > _t2; _t2 = _g ? _t3 : _t2; _u2 = _g ? _u3 : _u2;               \
    _g = _t5 > _t4; _t4 = _g ? _t5 : _t4; _u4 = _g ? _u5 : _u4;               \
    _g = _t7 > _t6; _t6 = _g ? _t7 : _t6; _u6 = _g ? _u7 : _u6;               \
    _g = _t2 > _t0; _t0 = _g ? _t2 : _t0; _u0 = _g ? _u2 : _u0;               \
    _g = _t6 > _t4; _t4 = _g ? _t6 : _t4; _u4 = _g ? _u6 : _u4;               \
    _g = _t4 > _t0; BV = _g ? _t4 : _t0; BJ = _g ? _u4 : _u0;                 \
  } while (0)

// one DPP fmax step: v = fmax(v, dpp_perm(v)); invalid lanes keep old v
#define DPP_FMAX(V, CTRL)                                                     \
  do {                                                                        \
    int _b = __builtin_amdgcn_update_dpp(                                     \
        __float_as_int(V), __float_as_int(V), (CTRL), 0xf, 0xf, false);       \
    (V) = fmaxf((V), __int_as_float(_b));                                     \
  } while (0)

// wave64 argmax at VALU speed: DPP max-reduce -> lane63 has max ->
// readlane broadcast -> ballot picks lowest matching lane -> readlane idx.
static __device__ __forceinline__ void wave_argmax(float bv, int bj,
                                                   float& wv, int& wj) {
    float v = bv;
    DPP_FMAX(v, 0x111);  // row_shr:1
    DPP_FMAX(v, 0x112);  // row_shr:2
    DPP_FMAX(v, 0x114);  // row_shr:4
    DPP_FMAX(v, 0x118);  // row_shr:8   -> lane15 of each row = row max
    DPP_FMAX(v, 0x142);  // row_bcast:15
    DPP_FMAX(v, 0x143);  // row_bcast:31 -> lane63 = wave max
    float wmax = __int_as_float(
        __builtin_amdgcn_readlane(__float_as_int(v), 63));
    unsigned long long m = __ballot(bv == wmax);
    int lowlane = __ffsll((unsigned long long)m) - 1;
    wj = __builtin_amdgcn_readlane(bj, lowlane);
    wv = wmax;
}

__global__ __launch_bounds__(256) void greedy_kernel(
        const float* __restrict__ cosine, const float* __restrict__ min2,
        float* __restrict__ sel_out, int L, int k) {
    const int tid = threadIdx.x;
    const int lane = tid & 63, wid = tid >> 6;
    __shared__ __align__(16) float sv[2][4];
    __shared__ __align__(16) int si[2][4];
    __shared__ int wsum[4];
    const int base = tid << 4;

#define DECL_SC(i) float sc##i;
    FOR16(DECL_SC)

    float bv; int bj;

    // ---- first = argmax(min2) ----
    {
        const float4* m4 = (const float4*)min2 + (tid << 2);
        float4 q0 = m4[0], q1 = m4[1], q2 = m4[2], q3 = m4[3];
        sc0 = q0.x;  sc1 = q0.y;  sc2 = q0.z;  sc3 = q0.w;
        sc4 = q1.x;  sc5 = q1.y;  sc6 = q1.z;  sc7 = q1.w;
        sc8 = q2.x;  sc9 = q2.y;  sc10 = q2.z; sc11 = q2.w;
        sc12 = q3.x; sc13 = q3.y; sc14 = q3.z; sc15 = q3.w;
    }
    ARGMAX16(bv, bj);
    {
        float wv; int wj;
        wave_argmax(bv, bj, wv, wj);
        if (lane == 0) { sv[0][wid] = wv; si[0][wid] = wj; }
    }
    __syncthreads();
    int first;
    {
        float4 cv4 = *(const float4*)&sv[0][0];
        int4 ci4 = *(const int4*)&si[0][0];
        float wv = cv4.x; int wi = ci4.x;
        if (cv4.y > wv || (cv4.y == wv && ci4.y < wi)) { wv = cv4.y; wi = ci4.y; }
        if (cv4.z > wv || (cv4.z == wv && ci4.z < wi)) { wv = cv4.z; wi = ci4.z; }
        if (cv4.w > wv || (cv4.w == wv && ci4.w < wi)) { wv = cv4.w; wi = ci4.w; }
        first = wi;
    }
    {
        const float4* rp = (const float4*)(cosine + (size_t)first * L) + (tid << 2);
        float4 q0 = rp[0], q1 = rp[1], q2 = rp[2], q3 = rp[3];
        int sl = ((first >> 4) == tid) ? (first & 15) : -1;
        sc0  = (sl == 0)  ? -INFINITY : q0.x;
        sc1  = (sl == 1)  ? -INFINITY : q0.y;
        sc2  = (sl == 2)  ? -INFINITY : q0.z;
        sc3  = (sl == 3)  ? -INFINITY : q0.w;
        sc4  = (sl == 4)  ? -INFINITY : q1.x;
        sc5  = (sl == 5)  ? -INFINITY : q1.y;
        sc6  = (sl == 6)  ? -INFINITY : q1.z;
        sc7  = (sl == 7)  ? -INFINITY : q1.w;
        sc8  = (sl == 8)  ? -INFINITY : q2.x;
        sc9  = (sl == 9)  ? -INFINITY : q2.y;
        sc10 = (sl == 10) ? -INFINITY : q2.z;
        sc11 = (sl == 11) ? -INFINITY : q2.w;
        sc12 = (sl == 12) ? -INFINITY : q3.x;
        sc13 = (sl == 13) ? -INFINITY : q3.y;
        sc14 = (sl == 14) ? -INFINITY : q3.z;
        sc15 = (sl == 15) ? -INFINITY : q3.w;
    }
    ARGMAX16(bv, bj);

    // ---- k-1 greedy steps, one barrier each ----
    int p = 1;
    for (int it = 0; it < k - 1; ++it) {
        float wv; int wj;
        wave_argmax(bv, bj, wv, wj);
        if (lane == 0) { sv[p][wid] = wv; si[p][wid] = wj; }
        __syncthreads();
        float4 cv4 = *(const float4*)&sv[p][0];
        int4 ci4 = *(const int4*)&si[p][0];
        p ^= 1;
        float cwv = cv4.x; int wi = ci4.x;
        if (cv4.y > cwv || (cv4.y == cwv && ci4.y < wi)) { cwv = cv4.y; wi = ci4.y; }
        if (cv4.z > cwv || (cv4.z == cwv && ci4.z < wi)) { cwv = cv4.z; wi = ci4.z; }
        if (cv4.w > cwv || (cv4.w == cwv && ci4.w < wi)) { cwv = cv4.w; wi = ci4.w; }
        const float4* rp = (const float4*)(cosine + (size_t)wi * L) + (tid << 2);
        float4 q0 = rp[0], q1 = rp[1], q2 = rp[2], q3 = rp[3];
        int sl = ((wi >> 4) == tid) ? (wi & 15) : -1;
        sc0  = (sl == 0)  ? -INFINITY : fminf(sc0, q0.x);
        sc1  = (sl == 1)  ? -INFINITY : fminf(sc1, q0.y);
        sc2  = (sl == 2)  ? -INFINITY : fminf(sc2, q0.z);
        sc3  = (sl == 3)  ? -INFINITY : fminf(sc3, q0.w);
        sc4  = (sl == 4)  ? -INFINITY : fminf(sc4, q1.x);
        sc5  = (sl == 5)  ? -INFINITY : fminf(sc5, q1.y);
        sc6  = (sl == 6)  ? -INFINITY : fminf(sc6, q1.z);
        sc7  = (sl == 7)  ? -INFINITY : fminf(sc7, q1.w);
        sc8  = (sl == 8)  ? -INFINITY : fminf(sc8, q2.x);
        sc9  = (sl == 9)  ? -INFINITY : fminf(sc9, q2.y);
        sc10 = (sl == 10) ? -INFINITY : fminf(sc10, q2.z);
        sc11 = (sl == 11) ? -INFINITY : fminf(sc11, q2.w);
        sc12 = (sl == 12) ? -INFINITY : fminf(sc12, q3.x);
        sc13 = (sl == 13) ? -INFINITY : fminf(sc13, q3.y);
        sc14 = (sl == 14) ? -INFINITY : fminf(sc14, q3.z);
        sc15 = (sl == 15) ? -INFINITY : fminf(sc15, q3.w);
        ARGMAX16(bv, bj);
    }

    // ---- compact selected (score == -inf) in ascending index order ----
    unsigned flags = 0; int cnt = 0;
#define FLAGBIT(i) if (sc##i == -INFINITY) { flags |= (1u << i); ++cnt; }
    FOR16(FLAGBIT)
    int incl = cnt;
#pragma unroll
    for (int off = 1; off < 64; off <<= 1) {
        int n = __shfl_up(incl, off, 64);
        if (lane >= off) incl += n;
    }
    if (lane == 63) wsum[wid] = incl;
    __syncthreads();
    int off0 = 0;
#pragma unroll
    for (int w = 0; w < 4; ++w)
        if (w < wid) off0 += wsum[w];
    int pos = off0 + incl - cnt;
#pragma unroll
    for (int j = 0; j < 16; ++j)
        if ((flags >> j) & 1) sel_out[pos++] = (float)(base + j);
}

// ---------------- launch ----------------
extern "C" void kernel_launch(void* const* d_in, const int* in_sizes, int n_in,
                              void* d_out, int out_size, void* d_ws, size_t ws_size,
                              hipStream_t stream) {
    const float* x = (const float*)d_in[0];

    long long L = (long long)floor(sqrt((double)out_size));
    while (L * L > (long long)out_size) --L;
    while ((L + 1) * (L + 1) <= (long long)out_size) ++L;
    long long k = (long long)out_size - L * L;
    long long C = (long long)in_sizes[0] / L;

    float* sel = (float*)d_out;
    float* cosine = (float*)d_out + k;
    float* rnorm = (float*)d_ws;
    float* min2 = rnorm + L;

    rownorm_kernel<<<(int)L, 256, 0, stream>>>(x, rnorm, (int)C);
    dim3 g2((int)(L / BN), (int)(L / BM));
    cosine_gemm<<<g2, 256, 0, stream>>>(x, rnorm, cosine, (int)L, (int)C);
    twosmallest_kernel<<<(int)L, 256, 0, stream>>>(cosine, min2, (int)L);
    greedy_kernel<<<1, 256, 0, stream>>>(cosine, min2, sel, (int)L, (int)k);
}

// Round 6
// 1270.363 us; speedup vs baseline: 2.0422x; 1.3048x over previous
//
#include <hip/hip_runtime.h>
#include <math.h>

// ---------------- Kernel A: reciprocal row norms ----------------
__global__ void rownorm_kernel(const float* __restrict__ x,
                               float* __restrict__ rnorm, int C) {
    int row = blockIdx.x;
    const float4* xr = (const float4*)(x + (size_t)row * C);
    int n4 = C >> 2;
    float s = 0.f;
    for (int c = threadIdx.x; c < n4; c += blockDim.x) {
        float4 v = xr[c];
        s += v.x * v.x + v.y * v.y + v.z * v.z + v.w * v.w;
    }
    for (int off = 32; off > 0; off >>= 1) s += __shfl_down(s, off, 64);
    __shared__ float red[4];
    int lane = threadIdx.x & 63, wid = threadIdx.x >> 6;
    if (lane == 0) red[wid] = s;
    __syncthreads();
    if (threadIdx.x == 0) {
        float t = red[0] + red[1] + red[2] + red[3];
        float n = fmaxf(sqrtf(t), 1e-6f);
        rnorm[row] = 1.0f / n;
    }
}

// ---------------- Kernel B: cosine = 1 - xn @ xn^T (fp32 vector GEMM) ------
#define BM 128
#define BN 128
#define BK 32

__global__ __launch_bounds__(256) void cosine_gemm(
        const float* __restrict__ x, const float* __restrict__ rnorm,
        float* __restrict__ cosine, int L, int C) {
    __shared__ float As[BK][BM + 4];
    __shared__ float Bs[BK][BN + 4];
    const int tid = threadIdx.x;
    const int i0 = blockIdx.y * BM;
    const int j0 = blockIdx.x * BN;
    const int tr = (tid >> 4) << 3;
    const int tc = (tid & 15) << 3;
    const int lr = tid >> 3;
    const int lc = (tid & 7) << 2;
    float acc[8][8] = {};

    for (int k0 = 0; k0 < C; k0 += BK) {
#pragma unroll
        for (int q = 0; q < 4; ++q) {
            int r = lr + q * 32;
            float ra = rnorm[i0 + r];
            float4 va = *(const float4*)(x + (size_t)(i0 + r) * C + k0 + lc);
            As[lc + 0][r] = va.x * ra;
            As[lc + 1][r] = va.y * ra;
            As[lc + 2][r] = va.z * ra;
            As[lc + 3][r] = va.w * ra;
            float rb = rnorm[j0 + r];
            float4 vb = *(const float4*)(x + (size_t)(j0 + r) * C + k0 + lc);
            Bs[lc + 0][r] = vb.x * rb;
            Bs[lc + 1][r] = vb.y * rb;
            Bs[lc + 2][r] = vb.z * rb;
            Bs[lc + 3][r] = vb.w * rb;
        }
        __syncthreads();
#pragma unroll
        for (int kk = 0; kk < BK; ++kk) {
            float a[8], b[8];
#pragma unroll
            for (int m = 0; m < 8; ++m) a[m] = As[kk][tr + m];
#pragma unroll
            for (int n = 0; n < 8; ++n) b[n] = Bs[kk][tc + n];
#pragma unroll
            for (int m = 0; m < 8; ++m)
#pragma unroll
                for (int n = 0; n < 8; ++n)
                    acc[m][n] = fmaf(a[m], b[n], acc[m][n]);
        }
        __syncthreads();
    }
#pragma unroll
    for (int m = 0; m < 8; ++m) {
        float* crow = cosine + (size_t)(i0 + tr + m) * L + j0 + tc;
        float4 o0 = {1.f - acc[m][0], 1.f - acc[m][1], 1.f - acc[m][2], 1.f - acc[m][3]};
        float4 o1 = {1.f - acc[m][4], 1.f - acc[m][5], 1.f - acc[m][6], 1.f - acc[m][7]};
        ((float4*)crow)[0] = o0;
        ((float4*)crow)[1] = o1;
    }
}

// ---------------- Kernel C: second-smallest per row ----------------
// 4 independent (m1,m2) pairs per thread (breaks the serial dependency
// chain so the 4 float4 loads overlap), branchless updates, merged at end.
__global__ void twosmallest_kernel(const float* __restrict__ cosine,
                                   float* __restrict__ min2, int L) {
    int row = blockIdx.x;
    const float4* r4 = (const float4*)(cosine + (size_t)row * L);
    float4 v0 = r4[threadIdx.x];
    float4 v1 = r4[threadIdx.x + 256];
    float4 v2 = r4[threadIdx.x + 512];
    float4 v3 = r4[threadIdx.x + 768];

#define PAIR_INIT(M1, M2, V)                                   \
    float M1 = fminf(V.x, V.y), M2 = fmaxf(V.x, V.y);          \
    { float _n1 = fminf(M1, V.z); M2 = fminf(M2, fmaxf(M1, V.z)); M1 = _n1; \
      _n1 = fminf(M1, V.w); M2 = fminf(M2, fmaxf(M1, V.w)); M1 = _n1; }
    PAIR_INIT(a1, a2, v0)
    PAIR_INIT(b1, b2, v1)
    PAIR_INIT(c1, c2, v2)
    PAIR_INIT(d1, d2, v3)
#undef PAIR_INIT
    // merge 4 pairs -> 1
    float m1 = fminf(a1, b1), m2 = fminf(fmaxf(a1, b1), fminf(a2, b2));
    float n1 = fminf(c1, d1), n2 = fminf(fmaxf(c1, d1), fminf(c2, d2));
    float t1 = fminf(m1, n1), t2 = fminf(fmaxf(m1, n1), fminf(m2, n2));
    float m1r = t1, m2r = t2;

    for (int off = 32; off > 0; off >>= 1) {
        float om1 = __shfl_down(m1r, off, 64);
        float om2 = __shfl_down(m2r, off, 64);
        float nm1 = fminf(m1r, om1);
        float nm2 = fminf(fmaxf(m1r, om1), fminf(m2r, om2));
        m1r = nm1; m2r = nm2;
    }
    __shared__ float s1[4], s2[4];
    int lane = threadIdx.x & 63, wid = threadIdx.x >> 6;
    if (lane == 0) { s1[wid] = m1r; s2[wid] = m2r; }
    __syncthreads();
    if (threadIdx.x == 0) {
        float x1 = s1[0], x2 = s2[0];
        for (int w = 1; w < 4; ++w) {
            float y1 = s1[w], y2 = s2[w];
            float z2 = fminf(fmaxf(x1, y1), fminf(x2, y2));
            x1 = fminf(x1, y1);
            x2 = z2;
        }
        min2[row] = x2;
    }
}

// ---------------- Kernel D: persistent greedy k-center ----------------
// 1 block x 256 threads (4 waves). Thread t owns scores [16t,16t+16) in 16
// named scalars. Per step: tournament local argmax -> DPP wave max-reduce
// + ballot/readlane argmax -> LDS slot combine (one barrier) -> winner row
// load + RUNNER-UP ROW PREFETCH (predicted next winner; consumed next
// iteration, so no vmcnt stall) -> fused fmin + -inf poke.
#define FOR16(X) X(0) X(1) X(2) X(3) X(4) X(5) X(6) X(7) \
                 X(8) X(9) X(10) X(11) X(12) X(13) X(14) X(15)

#define ARGMAX16(BV, BJ)                                                      \
  do {                                                                        \
    float _t0,_t1,_t2,_t3,_t4,_t5,_t6,_t7;                                    \
    int _u0,_u1,_u2,_u3,_u4,_u5,_u6,_u7;                                      \
    bool _g;                                                                  \
    _g = sc1  > sc0;  _t0 = _g ? sc1  : sc0;  _u0 = _g ? base+1  : base+0;    \
    _g = sc3  > sc2;  _t1 = _g ? sc3  : sc2;  _u1 = _g ? base+3  : base+2;    \
    _g = sc5  > sc4;  _t2 = _g ? sc5  : sc4;  _u2 = _g ? base+5  : base+4;    \
    _g = sc7  > sc6;  _t3 = _g ? sc7  : sc6;  _u3 = _g ? base+7  : base+6;    \
    _g = sc9  > sc8;  _t4 = _g ? sc9  : sc8;  _u4 = _g ? base+9  : base+8;    \
    _g = sc11 > sc10; _t5 = _g ? sc11 : sc10; _u5 = _g ? base+11 : base+10;   \
    _g = sc13 > sc12; _t6 = _g ? sc13 : sc12; _u6 = _g ? base+13 : base+12;   \
    _g = sc15 > sc14; _t7 = _g ? sc15 : sc14; _u7 = _g ? base+15 : base+14;   \
    _g = _t1 > _t0; _t0 = _g ? _t1 : _t0; _u0 = _g ? _u1 : _u0;               \
    _g = _t3 > _t2; _t2 = _g ? _t3 : _t2; _u2 = _g ? _u3 : _u2;               \
    _g = _t5 > _t4; _t4 = _g ? _t5 : _t4; _u4 = _g ? _u5 : _u4;               \
    _g = _t7 > _t6; _t6 = _g ? _t7 : _t6; _u6 = _g ? _u7 : _u6;               \
    _g = _t2 > _t0; _t0 = _g ? _t2 : _t0; _u0 = _g ? _u2 : _u0;               \
    _g = _t6 > _t4; _t4 = _g ? _t6 : _t4; _u4 = _g ? _u6 : _u4;               \
    _g = _t4 > _t0; BV = _g ? _t4 : _t0; BJ = _g ? _u4 : _u0;                 \
  } while (0)

#define DPP_FMAX(V, CTRL)                                                     \
  do {                                                                        \
    int _b = __builtin_amdgcn_update_dpp(                                     \
        __float_as_int(V), __float_as_int(V), (CTRL), 0xf, 0xf, false);       \
    (V) = fmaxf((V), __int_as_float(_b));                                     \
  } while (0)

static __device__ __forceinline__ void wave_argmax(float bv, int bj,
                                                   float& wv, int& wj) {
    float v = bv;
    DPP_FMAX(v, 0x111);  // row_shr:1
    DPP_FMAX(v, 0x112);  // row_shr:2
    DPP_FMAX(v, 0x114);  // row_shr:4
    DPP_FMAX(v, 0x118);  // row_shr:8
    DPP_FMAX(v, 0x142);  // row_bcast:15
    DPP_FMAX(v, 0x143);  // row_bcast:31 -> lane63 = wave max
    float wmax = __int_as_float(
        __builtin_amdgcn_readlane(__float_as_int(v), 63));
    unsigned long long m = __ballot(bv == wmax);
    int lowlane = __ffsll((unsigned long long)m) - 1;
    wj = __builtin_amdgcn_readlane(bj, lowlane);
    wv = wmax;
}

__global__ __launch_bounds__(256) void greedy_kernel(
        const float* __restrict__ cosine, const float* __restrict__ min2,
        float* __restrict__ sel_out, int L, int k) {
    const int tid = threadIdx.x;
    const int lane = tid & 63, wid = tid >> 6;
    __shared__ __align__(16) float sv[2][4];
    __shared__ __align__(16) int si[2][4];
    __shared__ int wsum[4];
    const int base = tid << 4;

#define DECL_SC(i) float sc##i;
    FOR16(DECL_SC)

    float bv; int bj;

    // ---- first = argmax(min2) ----
    {
        const float4* m4 = (const float4*)min2 + (tid << 2);
        float4 q0 = m4[0], q1 = m4[1], q2 = m4[2], q3 = m4[3];
        sc0 = q0.x;  sc1 = q0.y;  sc2 = q0.z;  sc3 = q0.w;
        sc4 = q1.x;  sc5 = q1.y;  sc6 = q1.z;  sc7 = q1.w;
        sc8 = q2.x;  sc9 = q2.y;  sc10 = q2.z; sc11 = q2.w;
        sc12 = q3.x; sc13 = q3.y; sc14 = q3.z; sc15 = q3.w;
    }
    ARGMAX16(bv, bj);
    {
        float wv; int wj;
        wave_argmax(bv, bj, wv, wj);
        if (lane == 0) { sv[0][wid] = wv; si[0][wid] = wj; }
    }
    __syncthreads();
    int first;
    {
        float4 cv4 = *(const float4*)&sv[0][0];
        int4 ci4 = *(const int4*)&si[0][0];
        float wv = cv4.x; int wi = ci4.x;
        if (cv4.y > wv || (cv4.y == wv && ci4.y < wi)) { wv = cv4.y; wi = ci4.y; }
        if (cv4.z > wv || (cv4.z == wv && ci4.z < wi)) { wv = cv4.z; wi = ci4.z; }
        if (cv4.w > wv || (cv4.w == wv && ci4.w < wi)) { wv = cv4.w; wi = ci4.w; }
        first = wi;
    }
    {
        const float4* rp = (const float4*)(cosine + (size_t)first * L) + (tid << 2);
        float4 q0 = rp[0], q1 = rp[1], q2 = rp[2], q3 = rp[3];
        int sl = ((first >> 4) == tid) ? (first & 15) : -1;
        sc0  = (sl == 0)  ? -INFINITY : q0.x;
        sc1  = (sl == 1)  ? -INFINITY : q0.y;
        sc2  = (sl == 2)  ? -INFINITY : q0.z;
        sc3  = (sl == 3)  ? -INFINITY : q0.w;
        sc4  = (sl == 4)  ? -INFINITY : q1.x;
        sc5  = (sl == 5)  ? -INFINITY : q1.y;
        sc6  = (sl == 6)  ? -INFINITY : q1.z;
        sc7  = (sl == 7)  ? -INFINITY : q1.w;
        sc8  = (sl == 8)  ? -INFINITY : q2.x;
        sc9  = (sl == 9)  ? -INFINITY : q2.y;
        sc10 = (sl == 10) ? -INFINITY : q2.z;
        sc11 = (sl == 11) ? -INFINITY : q2.w;
        sc12 = (sl == 12) ? -INFINITY : q3.x;
        sc13 = (sl == 13) ? -INFINITY : q3.y;
        sc14 = (sl == 14) ? -INFINITY : q3.z;
        sc15 = (sl == 15) ? -INFINITY : q3.w;
    }
    ARGMAX16(bv, bj);

    // ---- k-1 greedy steps, one barrier each ----
    float pf = 0.f, dummy = 0.f;
    int p = 1;
    for (int it = 0; it < k - 1; ++it) {
        float wv; int wj;
        wave_argmax(bv, bj, wv, wj);
        dummy += pf;  // consume last iter's prefetch (arrived long ago)
        if (lane == 0) { sv[p][wid] = wv; si[p][wid] = wj; }
        __syncthreads();
        float4 cv4 = *(const float4*)&sv[p][0];
        int4 ci4 = *(const int4*)&si[p][0];
        p ^= 1;
        float cwv = cv4.x; int wi = ci4.x; int wsl = 0;
        if (cv4.y > cwv || (cv4.y == cwv && ci4.y < wi)) { cwv = cv4.y; wi = ci4.y; wsl = 1; }
        if (cv4.z > cwv || (cv4.z == cwv && ci4.z < wi)) { cwv = cv4.z; wi = ci4.z; wsl = 2; }
        if (cv4.w > cwv || (cv4.w == cwv && ci4.w < wi)) { cwv = cv4.w; wi = ci4.w; wsl = 3; }
        // winner row loads (critical path) — issue first
        const float4* rp = (const float4*)(cosine + (size_t)wi * L) + (tid << 2);
        float4 q0 = rp[0], q1 = rp[1], q2 = rp[2], q3 = rp[3];
        // runner-up = best loser slot -> prefetch its row (predicted next)
        {
            float e0 = (wsl == 0) ? -INFINITY : cv4.x;
            float e1 = (wsl == 1) ? -INFINITY : cv4.y;
            float e2 = (wsl == 2) ? -INFINITY : cv4.z;
            float e3 = (wsl == 3) ? -INFINITY : cv4.w;
            float rv = e0; int ri = ci4.x;
            if (e1 > rv) { rv = e1; ri = ci4.y; }
            if (e2 > rv) { rv = e2; ri = ci4.z; }
            if (e3 > rv) { rv = e3; ri = ci4.w; }
            pf = *(cosine + (size_t)ri * L + (tid << 4));  // 64B-stride touch
        }
        int sl = ((wi >> 4) == tid) ? (wi & 15) : -1;
        sc0  = (sl == 0)  ? -INFINITY : fminf(sc0, q0.x);
        sc1  = (sl == 1)  ? -INFINITY : fminf(sc1, q0.y);
        sc2  = (sl == 2)  ? -INFINITY : fminf(sc2, q0.z);
        sc3  = (sl == 3)  ? -INFINITY : fminf(sc3, q0.w);
        sc4  = (sl == 4)  ? -INFINITY : fminf(sc4, q1.x);
        sc5  = (sl == 5)  ? -INFINITY : fminf(sc5, q1.y);
        sc6  = (sl == 6)  ? -INFINITY : fminf(sc6, q1.z);
        sc7  = (sl == 7)  ? -INFINITY : fminf(sc7, q1.w);
        sc8  = (sl == 8)  ? -INFINITY : fminf(sc8, q2.x);
        sc9  = (sl == 9)  ? -INFINITY : fminf(sc9, q2.y);
        sc10 = (sl == 10) ? -INFINITY : fminf(sc10, q2.z);
        sc11 = (sl == 11) ? -INFINITY : fminf(sc11, q2.w);
        sc12 = (sl == 12) ? -INFINITY : fminf(sc12, q3.x);
        sc13 = (sl == 13) ? -INFINITY : fminf(sc13, q3.y);
        sc14 = (sl == 14) ? -INFINITY : fminf(sc14, q3.z);
        sc15 = (sl == 15) ? -INFINITY : fminf(sc15, q3.w);
        ARGMAX16(bv, bj);
    }
    asm volatile("" :: "v"(dummy), "v"(pf));  // keep prefetch alive (no DCE)

    // ---- compact selected (score == -inf) in ascending index order ----
    unsigned flags = 0; int cnt = 0;
#define FLAGBIT(i) if (sc##i == -INFINITY) { flags |= (1u << i); ++cnt; }
    FOR16(FLAGBIT)
    int incl = cnt;
#pragma unroll
    for (int off = 1; off < 64; off <<= 1) {
        int n = __shfl_up(incl, off, 64);
        if (lane >= off) incl += n;
    }
    if (lane == 63) wsum[wid] = incl;
    __syncthreads();
    int off0 = 0;
#pragma unroll
    for (int w = 0; w < 4; ++w)
        if (w < wid) off0 += wsum[w];
    int pos = off0 + incl - cnt;
#pragma unroll
    for (int j = 0; j < 16; ++j)
        if ((flags >> j) & 1) sel_out[pos++] = (float)(base + j);
}

// ---------------- launch ----------------
extern "C" void kernel_launch(void* const* d_in, const int* in_sizes, int n_in,
                              void* d_out, int out_size, void* d_ws, size_t ws_size,
                              hipStream_t stream) {
    const float* x = (const float*)d_in[0];

    long long L = (long long)floor(sqrt((double)out_size));
    while (L * L > (long long)out_size) --L;
    while ((L + 1) * (L + 1) <= (long long)out_size) ++L;
    long long k = (long long)out_size - L * L;
    long long C = (long long)in_sizes[0] / L;

    float* sel = (float*)d_out;
    float* cosine = (float*)d_out + k;
    float* rnorm = (float*)d_ws;
    float* min2 = rnorm + L;

    rownorm_kernel<<<(int)L, 256, 0, stream>>>(x, rnorm, (int)C);
    dim3 g2((int)(L / BN), (int)(L / BM));
    cosine_gemm<<<g2, 256, 0, stream>>>(x, rnorm, cosine, (int)L, (int)C);
    twosmallest_kernel<<<(int)L, 256, 0, stream>>>(cosine, min2, (int)L);
    greedy_kernel<<<1, 256, 0, stream>>>(cosine, min2, sel, (int)L, (int)k);
}